// Round 10
// baseline (204.070 us; speedup 1.0000x reference)
//
#include <hip/hip_runtime.h>

#define BS 32
#define NA 512
#define ID 128
#define NH 8
#define HD 64
#define NHD 512   // NH*HD
#define NEG 0.2f
#define NC 32
#define CH 16
#define TROWS (NA + 1)   // 513 table rows per bh (row NA handles js==512)

// K1: h_prime = h @ W (fp32). Block = 32 rows x 512 cols, 4 waves: wave w has
// rows (w>>1)*16..+15 (wave-uniform -> A via s_load_dwordx4, zero LDS) and
// cols (w&1)*256 + 4*lane (dense 1KB W loads). 16 rows/wave halves the W
// re-read vs R7 (268->134 MB through L1/L2) at identical FMA count.
__global__ __launch_bounds__(256) void k1_gemm(
    const float* __restrict__ h, const float* __restrict__ W,
    const float* __restrict__ att, float* __restrict__ hp,
    float* __restrict__ s_out, float* __restrict__ t_out) {
  int blk = blockIdx.x;
  int b = blk >> 4;               // 16 blocks per batch
  int n0 = (blk & 15) * 32;
  int t = threadIdx.x;
  int lane = t & 63, w = t >> 6;
  int r0 = __builtin_amdgcn_readfirstlane((w >> 1) * 16);  // 0 or 16
  int chalf = __builtin_amdgcn_readfirstlane(w & 1);
  int col = chalf * 256 + lane * 4;
  int head = col >> 6;
  int d0 = col & 63;
  const float* arow = h + ((size_t)b * NA + n0 + r0) * ID;  // uniform base
  const float* wptr = W + col;

  float4 c0 = {0,0,0,0}, c1 = {0,0,0,0}, c2 = {0,0,0,0}, c3 = {0,0,0,0};
  float4 c4 = {0,0,0,0}, c5 = {0,0,0,0}, c6 = {0,0,0,0}, c7 = {0,0,0,0};
  float4 c8 = {0,0,0,0}, c9 = {0,0,0,0}, cA = {0,0,0,0}, cB = {0,0,0,0};
  float4 cC = {0,0,0,0}, cD = {0,0,0,0}, cE = {0,0,0,0}, cF = {0,0,0,0};

#define K1_ROW(I, C)                                                          \
  { float4 av = *(const float4*)(arow + (I) * ID + kc);                       \
    C.x += av.x*wv0.x + av.y*wv1.x + av.z*wv2.x + av.w*wv3.x;                 \
    C.y += av.x*wv0.y + av.y*wv1.y + av.z*wv2.y + av.w*wv3.y;                 \
    C.z += av.x*wv0.z + av.y*wv1.z + av.z*wv2.z + av.w*wv3.z;                 \
    C.w += av.x*wv0.w + av.y*wv1.w + av.z*wv2.w + av.w*wv3.w; }
  #pragma unroll 1
  for (int kc = 0; kc < ID; kc += 4) {
    float4 wv0 = *(const float4*)(wptr + (size_t)(kc + 0) * NHD);
    float4 wv1 = *(const float4*)(wptr + (size_t)(kc + 1) * NHD);
    float4 wv2 = *(const float4*)(wptr + (size_t)(kc + 2) * NHD);
    float4 wv3 = *(const float4*)(wptr + (size_t)(kc + 3) * NHD);
    K1_ROW( 0, c0) K1_ROW( 1, c1) K1_ROW( 2, c2) K1_ROW( 3, c3)
    K1_ROW( 4, c4) K1_ROW( 5, c5) K1_ROW( 6, c6) K1_ROW( 7, c7)
    K1_ROW( 8, c8) K1_ROW( 9, c9) K1_ROW(10, cA) K1_ROW(11, cB)
    K1_ROW(12, cC) K1_ROW(13, cD) K1_ROW(14, cE) K1_ROW(15, cF)
  }
#undef K1_ROW
  {
    size_t off = ((((size_t)b * NH + head) * NA) + (n0 + r0)) * HD + d0;
    *(float4*)(hp + off) = c0; off += HD; *(float4*)(hp + off) = c1; off += HD;
    *(float4*)(hp + off) = c2; off += HD; *(float4*)(hp + off) = c3; off += HD;
    *(float4*)(hp + off) = c4; off += HD; *(float4*)(hp + off) = c5; off += HD;
    *(float4*)(hp + off) = c6; off += HD; *(float4*)(hp + off) = c7; off += HD;
    *(float4*)(hp + off) = c8; off += HD; *(float4*)(hp + off) = c9; off += HD;
    *(float4*)(hp + off) = cA; off += HD; *(float4*)(hp + off) = cB; off += HD;
    *(float4*)(hp + off) = cC; off += HD; *(float4*)(hp + off) = cD; off += HD;
    *(float4*)(hp + off) = cE; off += HD; *(float4*)(hp + off) = cF;
  }
  // fused s/t: dot each acc row with att_a, reduce over the 16 lanes per head
  {
    float4 as4 = *(const float4*)(att + head * 128 + d0);
    float4 ad4 = *(const float4*)(att + head * 128 + 64 + d0);
#define DOT4(C, A) ((C).x*(A).x + (C).y*(A).y + (C).z*(A).z + (C).w*(A).w)
    float sp[16], tp[16];
    sp[ 0]=DOT4(c0,as4); tp[ 0]=DOT4(c0,ad4); sp[ 1]=DOT4(c1,as4); tp[ 1]=DOT4(c1,ad4);
    sp[ 2]=DOT4(c2,as4); tp[ 2]=DOT4(c2,ad4); sp[ 3]=DOT4(c3,as4); tp[ 3]=DOT4(c3,ad4);
    sp[ 4]=DOT4(c4,as4); tp[ 4]=DOT4(c4,ad4); sp[ 5]=DOT4(c5,as4); tp[ 5]=DOT4(c5,ad4);
    sp[ 6]=DOT4(c6,as4); tp[ 6]=DOT4(c6,ad4); sp[ 7]=DOT4(c7,as4); tp[ 7]=DOT4(c7,ad4);
    sp[ 8]=DOT4(c8,as4); tp[ 8]=DOT4(c8,ad4); sp[ 9]=DOT4(c9,as4); tp[ 9]=DOT4(c9,ad4);
    sp[10]=DOT4(cA,as4); tp[10]=DOT4(cA,ad4); sp[11]=DOT4(cB,as4); tp[11]=DOT4(cB,ad4);
    sp[12]=DOT4(cC,as4); tp[12]=DOT4(cC,ad4); sp[13]=DOT4(cD,as4); tp[13]=DOT4(cD,ad4);
    sp[14]=DOT4(cE,as4); tp[14]=DOT4(cE,ad4); sp[15]=DOT4(cF,as4); tp[15]=DOT4(cF,ad4);
#undef DOT4
    #pragma unroll
    for (int m = 1; m < 16; m <<= 1) {
      #pragma unroll
      for (int i = 0; i < 16; ++i) {
        sp[i] += __shfl_xor(sp[i], m, 64);
        tp[i] += __shfl_xor(tp[i], m, 64);
      }
    }
    int g16 = lane & 15;
    float sv_ = sp[0], tv_ = tp[0];
    #pragma unroll
    for (int i = 1; i < 16; ++i) if (g16 == i) { sv_ = sp[i]; tv_ = tp[i]; }
    size_t off = (((size_t)b * NH + head) * NA) + n0 + r0 + g16;
    s_out[off] = sv_;
    t_out[off] = tv_;
  }
}

// K2a: per-(b,h): hybrid bitonic sort of t, per-wave local sums + cross-wave
// scan, exact scalar den tables, then ONE forward stream writing both full
// tables (sufP via totP - preP subtraction — validated R8). 128 gathers/wave.
__global__ __launch_bounds__(512) void k2a_tables(
    const float* __restrict__ hp, const float* __restrict__ s_g,
    const float* __restrict__ t_g, float* __restrict__ sufPfull,
    float* __restrict__ preNfull, float4* __restrict__ rinfo_g) {
  __shared__ float tv[NA]; __shared__ int tpm[NA];
  __shared__ float wp[NA]; __shared__ float wn[NA];
  __shared__ float localP[8 * 64]; __shared__ float localN[8 * 64];
  __shared__ float seedP[8 * 64];  __shared__ float seedN[8 * 64];
  __shared__ float totP[64]; __shared__ float totN[64];
  __shared__ float zps[NA + 1]; __shared__ float znp[NA + 1];
  __shared__ float szP[NC]; __shared__ float szN[NC];
  __shared__ float sufZ[NC + 1]; __shared__ float preZ[NC + 1];
  __shared__ float smax8[8];

  int bh = blockIdx.x;
  int t = threadIdx.x;
  int lane = t & 63, w = t >> 6;
  const float* vbase = hp + (size_t)bh * NA * HD;

  // hybrid bitonic sort of t ascending (regs + shfl <64, LDS >=64)
  float tvr = t_g[(size_t)bh * NA + t];
  int tir = t;
  for (int size = 2; size <= NA; size <<= 1) {
    bool dirAsc = ((t & size) == 0);
    for (int stride = size >> 1; stride > 0; stride >>= 1) {
      float pv; int pi;
      if (stride >= 64) {
        tv[t] = tvr; tpm[t] = tir;
        __syncthreads();
        pv = tv[t ^ stride]; pi = tpm[t ^ stride];
        __syncthreads();
      } else {
        pv = __shfl_xor(tvr, stride, 64);
        pi = __shfl_xor(tir, stride, 64);
      }
      bool mn = (((t & stride) == 0) == dirAsc);
      bool sw = mn ? (pv < tvr) : (pv > tvr);
      if (sw) { tvr = pv; tir = pi; }
    }
  }
  tv[t] = tvr; tpm[t] = tir;
  float sval = s_g[(size_t)bh * NA + t];
  {
    float m = sval;
    #pragma unroll
    for (int d = 32; d; d >>= 1) m = fmaxf(m, __shfl_xor(m, d, 64));
    if (lane == 0) smax8[w] = m;
  }
  __syncthreads();

  float cmax = fmaxf(tv[NA - 1], 0.f);
  float amax = fmaxf(fmaxf(fmaxf(smax8[0], smax8[1]), fmaxf(smax8[2], smax8[3])),
                     fmaxf(fmaxf(smax8[4], smax8[5]), fmaxf(smax8[6], smax8[7])));
  amax = fmaxf(amax, 0.f);
  wp[t] = __expf(tv[t] - cmax);
  wn[t] = __expf(NEG * tv[t] - cmax);
  __syncthreads();

  // pass 1: per-wave local vector sums over own 64 sorted rows (64 gathers)
  {
    float aP = 0.f, aN = 0.f;
    int jb = w * 64;
    #pragma unroll 4
    for (int jj = 0; jj < 64; ++jj) {
      int j = jb + jj;
      float vv = vbase[(size_t)tpm[j] * HD + lane];
      aP += wp[j] * vv;
      aN += wn[j] * vv;
    }
    localP[w * 64 + lane] = aP;
    localN[w * 64 + lane] = aN;
  }
  // scalar 16-chunk sums for exact den tables
  if (t < 32) {
    float a = 0.f;
    for (int j = t * CH; j < t * CH + CH; ++j) a += wp[j];
    szP[t] = a;
  } else if (t < 64) {
    int c = t - 32; float a = 0.f;
    for (int j = c * CH; j < c * CH + CH; ++j) a += wn[j];
    szN[c] = a;
  }
  __syncthreads();

  // scans: scalar chunk scans + cross-wave vector scans
  if (t == 0) {
    float run = 0.f; sufZ[NC] = 0.f;
    for (int cc = NC - 1; cc >= 0; --cc) { run += szP[cc]; sufZ[cc] = run; }
  } else if (t == 1) {
    float run = 0.f;
    for (int cc = 0; cc <= NC; ++cc) { preZ[cc] = run; if (cc < NC) run += szN[cc]; }
  } else if (t >= 64 && t < 128) {
    int d = t - 64; float run = 0.f;
    for (int u = 0; u < 8; ++u) { seedP[u * 64 + d] = run; run += localP[u * 64 + d]; }
    totP[d] = run;
  } else if (t >= 128 && t < 192) {
    int d = t - 128; float run = 0.f;
    for (int u = 0; u < 8; ++u) { seedN[u * 64 + d] = run; run += localN[u * 64 + d]; }
    totN[d] = run;
  }
  __syncthreads();

  // exact full-res scalar tables: zps (suffix of wp), znp (prefix of wn)
  {
    int ch = t >> 4;
    float a = 0.f;
    for (int k = t; k < ch * CH + CH; ++k) a += wp[k];
    zps[t] = a + sufZ[ch + 1];
    float b2 = 0.f;
    for (int k = ch * CH; k < t; ++k) b2 += wn[k];
    znp[t] = preZ[ch] + b2;
    if (t == 0) { zps[NA] = 0.f; znp[NA] = preZ[NC]; }
  }
  __syncthreads();

  // pass 2: ONE forward stream writes both tables (write-before-update)
  {
    float* sP = sufPfull + (size_t)bh * TROWS * 64;
    float* pN = preNfull + (size_t)bh * TROWS * 64;
    int jb = w * 64;
    float runP = seedP[w * 64 + lane];
    float runN = seedN[w * 64 + lane];
    float totPd = totP[lane];
    #pragma unroll 4
    for (int jj = 0; jj < 64; ++jj) {
      int j = jb + jj;
      sP[(size_t)j * 64 + lane] = totPd - runP;
      pN[(size_t)j * 64 + lane] = runN;
      float vv = vbase[(size_t)tpm[j] * HD + lane];
      runP += wp[j] * vv;
      runN += wn[j] * vv;
    }
    if (t < 64) {
      sP[(size_t)NA * 64 + t] = 0.f;
      pN[(size_t)NA * 64 + t] = totN[t];
    }
  }

  // per-row info (thread t = original row t)
  {
    float A = __expf(sval - amax);
    float B = __expf(NEG * sval - amax);
    float key = -sval;
    int lo = 0, hi = NA;
    while (lo < hi) { int mid = (lo + hi) >> 1; if (tv[mid] < key) lo = mid + 1; else hi = mid; }
    int js = lo;
    float den = A * zps[js] + B * znp[js];
    float4 ri;
    ri.x = A; ri.y = B; ri.z = 1.f / den; ri.w = __int_as_float(js);
    rinfo_g[(size_t)bh * NA + t] = ri;
  }
}

// K2b: pure apply — no indirection, no LDS, no barriers. Proven R7.
__global__ __launch_bounds__(256) void k2b_apply(
    const float* __restrict__ sufPfull, const float* __restrict__ preNfull,
    const float4* __restrict__ rinfo_g, float* __restrict__ out) {
  int blk = blockIdx.x;           // 32768 blocks: bh = blk>>7, 4 rows/block
  int bh = blk >> 7;
  int row = (blk & 127) * 4 + (threadIdx.x >> 6);
  int lane = threadIdx.x & 63;
  float4 ri = rinfo_g[(size_t)bh * NA + row];
  int js = __float_as_int(ri.w);
  size_t tb = ((size_t)bh * TROWS + js) * 64 + lane;
  float x = (ri.x * sufPfull[tb] + ri.y * preNfull[tb]) * ri.z;
  out[(((size_t)bh * NA) + row) * 64 + lane] = x > 0.f ? x : __expf(x) - 1.f;
}

extern "C" void kernel_launch(void* const* d_in, const int* in_sizes, int n_in,
                              void* d_out, int out_size, void* d_ws, size_t ws_size,
                              hipStream_t stream) {
  const float* h  = (const float*)d_in[0];
  const float* W  = (const float*)d_in[1];
  const float* att = (const float*)d_in[2];
  float* out = (float*)d_out;
  // ws floats: hp 8.39M | s .131M | t .131M | sufPfull 8.40M | preNfull 8.40M
  // | rinfo 2.10M -> ~104 MB (ws_size is 256 MiB per harness fill evidence)
  float* hp    = (float*)d_ws;
  float* s_arr = hp + (size_t)BS * NH * NA * HD;
  float* t_arr = s_arr + (size_t)BS * NH * NA;
  float* sufPf = t_arr + (size_t)BS * NH * NA;
  float* preNf = sufPf + (size_t)BS * NH * TROWS * 64;
  float* rinfo = preNf + (size_t)BS * NH * TROWS * 64;

  k1_gemm   <<<dim3(512),   dim3(256), 0, stream>>>(h, W, att, hp, s_arr, t_arr);
  k2a_tables<<<dim3(256),   dim3(512), 0, stream>>>(hp, s_arr, t_arr, sufPf,
                                                    preNf, (float4*)rinfo);
  k2b_apply <<<dim3(32768), dim3(256), 0, stream>>>(sufPf, preNf,
                                                    (float4*)rinfo, out);
}

// Round 11
// 165.573 us; speedup vs baseline: 1.2325x; 1.2325x over previous
//
#include <hip/hip_runtime.h>

#define BS 32
#define NA 512
#define ID 128
#define NH 8
#define HD 64
#define NHD 512   // NH*HD
#define NEG 0.2f
#define NC 32
#define CH 16
#define TROWS (NA + 1)   // 513 table rows per bh (row NA handles js==512)

// K1: h_prime = h @ W (fp32). EXACT R7 version (proven <43us; R10's 16-row
// variant spilled at VGPR 48 => ~95us). Block = 16 rows x 512 cols, 4 waves:
// wave w: rows (w>>1)*8..+7 (wave-uniform -> A via s_load, zero LDS), cols
// (w&1)*256 + 4*lane (dense 1KB W loads).
__global__ __launch_bounds__(256) void k1_gemm(
    const float* __restrict__ h, const float* __restrict__ W,
    const float* __restrict__ att, float* __restrict__ hp,
    float* __restrict__ s_out, float* __restrict__ t_out) {
  int blk = blockIdx.x;
  int b = blk >> 5;
  int n0 = (blk & 31) * 16;
  int t = threadIdx.x;
  int lane = t & 63, w = t >> 6;
  int r0 = __builtin_amdgcn_readfirstlane((w >> 1) * 8);   // 0 or 8
  int chalf = __builtin_amdgcn_readfirstlane(w & 1);
  int col = chalf * 256 + lane * 4;
  int head = col >> 6;
  int d0 = col & 63;
  const float* arow = h + ((size_t)b * NA + n0 + r0) * ID;  // uniform base
  const float* wptr = W + col;

  float4 a0c = {0,0,0,0}, a1c = {0,0,0,0}, a2c = {0,0,0,0}, a3c = {0,0,0,0};
  float4 a4c = {0,0,0,0}, a5c = {0,0,0,0}, a6c = {0,0,0,0}, a7c = {0,0,0,0};

#define K1_ROW(I, C, KK)                                                      \
  { float a_ = arow[(I) * ID + kc + (KK)];                                    \
    C.x += a_ * wv.x; C.y += a_ * wv.y; C.z += a_ * wv.z; C.w += a_ * wv.w; }
  #pragma unroll 1
  for (int kc = 0; kc < ID; kc += 8) {
    #pragma unroll
    for (int kk = 0; kk < 8; ++kk) {
      float4 wv = *(const float4*)(wptr + (size_t)(kc + kk) * NHD);
      K1_ROW(0, a0c, kk) K1_ROW(1, a1c, kk) K1_ROW(2, a2c, kk)
      K1_ROW(3, a3c, kk) K1_ROW(4, a4c, kk) K1_ROW(5, a5c, kk)
      K1_ROW(6, a6c, kk) K1_ROW(7, a7c, kk)
    }
  }
#undef K1_ROW
  {
    size_t off = ((((size_t)b * NH + head) * NA) + (n0 + r0)) * HD + d0;
    *(float4*)(hp + off) = a0c; off += HD;
    *(float4*)(hp + off) = a1c; off += HD;
    *(float4*)(hp + off) = a2c; off += HD;
    *(float4*)(hp + off) = a3c; off += HD;
    *(float4*)(hp + off) = a4c; off += HD;
    *(float4*)(hp + off) = a5c; off += HD;
    *(float4*)(hp + off) = a6c; off += HD;
    *(float4*)(hp + off) = a7c;
  }
  {
    float4 as4 = *(const float4*)(att + head * 128 + d0);
    float4 ad4 = *(const float4*)(att + head * 128 + 64 + d0);
#define DOT4(C, A) ((C).x*(A).x + (C).y*(A).y + (C).z*(A).z + (C).w*(A).w)
    float sp0 = DOT4(a0c, as4), tp0 = DOT4(a0c, ad4);
    float sp1 = DOT4(a1c, as4), tp1 = DOT4(a1c, ad4);
    float sp2 = DOT4(a2c, as4), tp2 = DOT4(a2c, ad4);
    float sp3 = DOT4(a3c, as4), tp3 = DOT4(a3c, ad4);
    float sp4 = DOT4(a4c, as4), tp4 = DOT4(a4c, ad4);
    float sp5 = DOT4(a5c, as4), tp5 = DOT4(a5c, ad4);
    float sp6 = DOT4(a6c, as4), tp6 = DOT4(a6c, ad4);
    float sp7 = DOT4(a7c, as4), tp7 = DOT4(a7c, ad4);
#undef DOT4
    #pragma unroll
    for (int m = 1; m < 16; m <<= 1) {
      sp0 += __shfl_xor(sp0, m, 64); tp0 += __shfl_xor(tp0, m, 64);
      sp1 += __shfl_xor(sp1, m, 64); tp1 += __shfl_xor(tp1, m, 64);
      sp2 += __shfl_xor(sp2, m, 64); tp2 += __shfl_xor(tp2, m, 64);
      sp3 += __shfl_xor(sp3, m, 64); tp3 += __shfl_xor(tp3, m, 64);
      sp4 += __shfl_xor(sp4, m, 64); tp4 += __shfl_xor(tp4, m, 64);
      sp5 += __shfl_xor(sp5, m, 64); tp5 += __shfl_xor(tp5, m, 64);
      sp6 += __shfl_xor(sp6, m, 64); tp6 += __shfl_xor(tp6, m, 64);
      sp7 += __shfl_xor(sp7, m, 64); tp7 += __shfl_xor(tp7, m, 64);
    }
    int g16 = lane & 15;
    int rsel = g16 & 7;
    float sv_ = rsel == 0 ? sp0 : rsel == 1 ? sp1 : rsel == 2 ? sp2 :
                rsel == 3 ? sp3 : rsel == 4 ? sp4 : rsel == 5 ? sp5 :
                rsel == 6 ? sp6 : sp7;
    float tv_ = rsel == 0 ? tp0 : rsel == 1 ? tp1 : rsel == 2 ? tp2 :
                rsel == 3 ? tp3 : rsel == 4 ? tp4 : rsel == 5 ? tp5 :
                rsel == 6 ? tp6 : tp7;
    size_t off = (((size_t)b * NH + head) * NA) + n0 + r0 + rsel;
    if (g16 < 8) s_out[off] = sv_;
    else         t_out[off] = tv_;
  }
}

// K2a: per-(b,h): hybrid bitonic t-sort, per-wave local sums + cross-wave
// scan, exact scalar den tables, then ONE forward stream (unroll 16) writing
// the INTERLEAVED float2 {sufP = totP - runP, preN = runN} table (subtraction
// numerics validated R8/R10). 128 gathers/wave, one dwordx2 store per j.
__global__ __launch_bounds__(512) void k2a_tables(
    const float* __restrict__ hp, const float* __restrict__ s_g,
    const float* __restrict__ t_g, float2* __restrict__ tab,
    float4* __restrict__ rinfo_g) {
  __shared__ float tv[NA]; __shared__ int tpm[NA];
  __shared__ float wp[NA]; __shared__ float wn[NA];
  __shared__ float localP[8 * 64]; __shared__ float localN[8 * 64];
  __shared__ float seedP[8 * 64];  __shared__ float seedN[8 * 64];
  __shared__ float totP[64]; __shared__ float totN[64];
  __shared__ float zps[NA + 1]; __shared__ float znp[NA + 1];
  __shared__ float szP[NC]; __shared__ float szN[NC];
  __shared__ float sufZ[NC + 1]; __shared__ float preZ[NC + 1];
  __shared__ float smax8[8];

  int bh = blockIdx.x;
  int t = threadIdx.x;
  int lane = t & 63, w = t >> 6;
  const float* vbase = hp + (size_t)bh * NA * HD;

  // hybrid bitonic sort of t ascending (regs + shfl <64, LDS >=64)
  float tvr = t_g[(size_t)bh * NA + t];
  int tir = t;
  for (int size = 2; size <= NA; size <<= 1) {
    bool dirAsc = ((t & size) == 0);
    for (int stride = size >> 1; stride > 0; stride >>= 1) {
      float pv; int pi;
      if (stride >= 64) {
        tv[t] = tvr; tpm[t] = tir;
        __syncthreads();
        pv = tv[t ^ stride]; pi = tpm[t ^ stride];
        __syncthreads();
      } else {
        pv = __shfl_xor(tvr, stride, 64);
        pi = __shfl_xor(tir, stride, 64);
      }
      bool mn = (((t & stride) == 0) == dirAsc);
      bool sw = mn ? (pv < tvr) : (pv > tvr);
      if (sw) { tvr = pv; tir = pi; }
    }
  }
  tv[t] = tvr; tpm[t] = tir;
  float sval = s_g[(size_t)bh * NA + t];
  {
    float m = sval;
    #pragma unroll
    for (int d = 32; d; d >>= 1) m = fmaxf(m, __shfl_xor(m, d, 64));
    if (lane == 0) smax8[w] = m;
  }
  __syncthreads();

  float cmax = fmaxf(tv[NA - 1], 0.f);
  float amax = fmaxf(fmaxf(fmaxf(smax8[0], smax8[1]), fmaxf(smax8[2], smax8[3])),
                     fmaxf(fmaxf(smax8[4], smax8[5]), fmaxf(smax8[6], smax8[7])));
  amax = fmaxf(amax, 0.f);
  wp[t] = __expf(tv[t] - cmax);
  wn[t] = __expf(NEG * tv[t] - cmax);
  __syncthreads();

  // pass 1: per-wave local vector sums over own 64 sorted rows (64 gathers,
  // deep unroll for memory-level parallelism)
  {
    float aP = 0.f, aN = 0.f;
    int jb = w * 64;
    #pragma unroll 16
    for (int jj = 0; jj < 64; ++jj) {
      int j = jb + jj;
      float vv = vbase[(size_t)tpm[j] * HD + lane];
      aP += wp[j] * vv;
      aN += wn[j] * vv;
    }
    localP[w * 64 + lane] = aP;
    localN[w * 64 + lane] = aN;
  }
  // scalar 16-chunk sums for exact den tables
  if (t < 32) {
    float a = 0.f;
    for (int j = t * CH; j < t * CH + CH; ++j) a += wp[j];
    szP[t] = a;
  } else if (t < 64) {
    int c = t - 32; float a = 0.f;
    for (int j = c * CH; j < c * CH + CH; ++j) a += wn[j];
    szN[c] = a;
  }
  __syncthreads();

  // scans: scalar chunk scans + cross-wave vector scans
  if (t == 0) {
    float run = 0.f; sufZ[NC] = 0.f;
    for (int cc = NC - 1; cc >= 0; --cc) { run += szP[cc]; sufZ[cc] = run; }
  } else if (t == 1) {
    float run = 0.f;
    for (int cc = 0; cc <= NC; ++cc) { preZ[cc] = run; if (cc < NC) run += szN[cc]; }
  } else if (t >= 64 && t < 128) {
    int d = t - 64; float run = 0.f;
    for (int u = 0; u < 8; ++u) { seedP[u * 64 + d] = run; run += localP[u * 64 + d]; }
    totP[d] = run;
  } else if (t >= 128 && t < 192) {
    int d = t - 128; float run = 0.f;
    for (int u = 0; u < 8; ++u) { seedN[u * 64 + d] = run; run += localN[u * 64 + d]; }
    totN[d] = run;
  }
  __syncthreads();

  // exact full-res scalar tables: zps (suffix of wp), znp (prefix of wn)
  {
    int ch = t >> 4;
    float a = 0.f;
    for (int k = t; k < ch * CH + CH; ++k) a += wp[k];
    zps[t] = a + sufZ[ch + 1];
    float b2 = 0.f;
    for (int k = ch * CH; k < t; ++k) b2 += wn[k];
    znp[t] = preZ[ch] + b2;
    if (t == 0) { zps[NA] = 0.f; znp[NA] = preZ[NC]; }
  }
  __syncthreads();

  // pass 2: ONE forward stream writes the interleaved table
  {
    float2* tb2 = tab + (size_t)bh * TROWS * 64;
    int jb = w * 64;
    float runP = seedP[w * 64 + lane];
    float runN = seedN[w * 64 + lane];
    float totPd = totP[lane];
    #pragma unroll 16
    for (int jj = 0; jj < 64; ++jj) {
      int j = jb + jj;
      float2 e; e.x = totPd - runP; e.y = runN;
      tb2[(size_t)j * 64 + lane] = e;
      float vv = vbase[(size_t)tpm[j] * HD + lane];
      runP += wp[j] * vv;
      runN += wn[j] * vv;
    }
    if (t < 64) {
      float2 e; e.x = 0.f; e.y = totN[t];
      tb2[(size_t)NA * 64 + t] = e;
    }
  }

  // per-row info (thread t = original row t)
  {
    float A = __expf(sval - amax);
    float B = __expf(NEG * sval - amax);
    float key = -sval;
    int lo = 0, hi = NA;
    while (lo < hi) { int mid = (lo + hi) >> 1; if (tv[mid] < key) lo = mid + 1; else hi = mid; }
    int js = lo;
    float den = A * zps[js] + B * znp[js];
    float4 ri;
    ri.x = A; ri.y = B; ri.z = 1.f / den; ri.w = __int_as_float(js);
    rinfo_g[(size_t)bh * NA + t] = ri;
  }
}

// K2b: pure apply — one float2 load + one store per element.
__global__ __launch_bounds__(256) void k2b_apply(
    const float2* __restrict__ tab, const float4* __restrict__ rinfo_g,
    float* __restrict__ out) {
  int blk = blockIdx.x;           // 32768 blocks: bh = blk>>7, 4 rows/block
  int bh = blk >> 7;
  int row = (blk & 127) * 4 + (threadIdx.x >> 6);
  int lane = threadIdx.x & 63;
  float4 ri = rinfo_g[(size_t)bh * NA + row];
  int js = __float_as_int(ri.w);
  float2 pv = tab[((size_t)bh * TROWS + js) * 64 + lane];
  float x = (ri.x * pv.x + ri.y * pv.y) * ri.z;
  out[(((size_t)bh * NA) + row) * 64 + lane] = x > 0.f ? x : __expf(x) - 1.f;
}

extern "C" void kernel_launch(void* const* d_in, const int* in_sizes, int n_in,
                              void* d_out, int out_size, void* d_ws, size_t ws_size,
                              hipStream_t stream) {
  const float* h  = (const float*)d_in[0];
  const float* W  = (const float*)d_in[1];
  const float* att = (const float*)d_in[2];
  float* out = (float*)d_out;
  // ws floats: hp 8.39M | s .131M | t .131M | tab (float2) 16.8M | rinfo 2.10M
  float* hp    = (float*)d_ws;
  float* s_arr = hp + (size_t)BS * NH * NA * HD;
  float* t_arr = s_arr + (size_t)BS * NH * NA;
  float* tabf  = t_arr + (size_t)BS * NH * NA;
  float* rinfo = tabf + (size_t)BS * NH * TROWS * 64 * 2;

  k1_gemm   <<<dim3(1024),  dim3(256), 0, stream>>>(h, W, att, hp, s_arr, t_arr);
  k2a_tables<<<dim3(256),   dim3(512), 0, stream>>>(hp, s_arr, t_arr,
                                                    (float2*)tabf, (float4*)rinfo);
  k2b_apply <<<dim3(32768), dim3(256), 0, stream>>>((float2*)tabf,
                                                    (float4*)rinfo, out);
}